// Round 1
// baseline (5530.483 us; speedup 1.0000x reference)
//
#include <hip/hip_runtime.h>
#include <stdint.h>
#include <stddef.h>

#define D_MODEL 1024
#define NH 16
#define DKH 64
#define SEQ 2048
#define BATCH 4
#define LAYERS 6
#define DFF_N 4096
#define MROWS (BATCH*SEQ)   // 8192 token rows

typedef __attribute__((ext_vector_type(8))) __bf16 bf16x8;
typedef __attribute__((ext_vector_type(4))) float f32x4;
typedef unsigned int uint4a __attribute__((ext_vector_type(4), may_alias, aligned(16)));

__device__ __forceinline__ unsigned short f2b(float f) {
  union { float f; uint32_t u; } x; x.f = f;
  uint32_t u = x.u + 0x7fffu + ((x.u >> 16) & 1u);   // RNE
  return (unsigned short)(u >> 16);
}

__device__ __forceinline__ bf16x8 ld8(const unsigned short* p) {
  return __builtin_bit_cast(bf16x8, *(const uint4a*)p);
}

__device__ __forceinline__ void gload_lds16(const unsigned short* g, unsigned short* l) {
  // async 16B/lane global->LDS; LDS dest = wave-uniform base + lane*16
  __builtin_amdgcn_global_load_lds((const __attribute__((address_space(1))) void*)g,
                                   (__attribute__((address_space(3))) void*)l, 16, 0, 0);
}

// ---------------------------------------------------------------- transpose+cvt
// dst[c][r] = bf16(src[r][c]); src is R x C f32. grid (C/32, R/32), block 256.
__global__ __launch_bounds__(256)
void transpose_cvt(const float* __restrict__ src, unsigned short* __restrict__ dst,
                   int R, int C)
{
  __shared__ float tile[32][33];
  int tx = threadIdx.x & 31, ty = threadIdx.x >> 5;        // 32 x 8
  int c0 = blockIdx.x * 32, r0 = blockIdx.y * 32;
#pragma unroll
  for (int i = 0; i < 4; i++)
    tile[ty + i*8][tx] = src[(size_t)(r0 + ty + i*8)*C + c0 + tx];
  __syncthreads();
#pragma unroll
  for (int i = 0; i < 4; i++)
    dst[(size_t)(c0 + ty + i*8)*R + r0 + tx] = f2b(tile[tx][ty + i*8]);
}

// ---------------------------------------------------------------- embed + PE
__global__ __launch_bounds__(256)
void embed_kernel(const int* __restrict__ x, const float* __restrict__ emb,
                  float* __restrict__ h, unsigned short* __restrict__ hb)
{
  size_t idx = (size_t)blockIdx.x * 256 + threadIdx.x;     // over MROWS*D
  int d = (int)(idx & (D_MODEL - 1));
  size_t bs = idx >> 10;
  int s = (int)(bs & (SEQ - 1));
  int tok = x[bs];
  float val = emb[(size_t)tok * D_MODEL + d] * 32.0f;      // sqrt(1024)=32
  int i = d >> 1;
  float div = __expf(-0.017988946039016f * (float)i);       // exp(2i * -ln(1e4)/1024)
  float ang = (float)s * div;
  val += (d & 1) ? cosf(ang) : sinf(ang);
  h[idx] = val;
  hb[idx] = f2b(val);
}

// ---------------------------------------------------------------- LayerNorm
// one block per row; writes f32 (residual stream) and optional bf16 (GEMM A)
__global__ __launch_bounds__(256)
void ln_kernel(const float* __restrict__ in, const float* __restrict__ g,
               const float* __restrict__ be, float* __restrict__ outf,
               unsigned short* __restrict__ outb)
{
  int row = blockIdx.x;
  const float* xr = in + (size_t)row * D_MODEL;
  int t = threadIdx.x, lane = t & 63, w = t >> 6;
  float v[4];
#pragma unroll
  for (int i = 0; i < 4; i++) v[i] = xr[t + i*256];
  float s = v[0] + v[1] + v[2] + v[3];
#pragma unroll
  for (int off = 1; off < 64; off <<= 1) s += __shfl_xor(s, off);
  __shared__ float redA[4], redB[4];
  if (lane == 0) redA[w] = s;
  __syncthreads();
  float mu = (redA[0] + redA[1] + redA[2] + redA[3]) * (1.0f / D_MODEL);
  float q = 0.f;
#pragma unroll
  for (int i = 0; i < 4; i++) { float d = v[i] - mu; q += d * d; }
#pragma unroll
  for (int off = 1; off < 64; off <<= 1) q += __shfl_xor(q, off);
  if (lane == 0) redB[w] = q;
  __syncthreads();
  float var = (redB[0] + redB[1] + redB[2] + redB[3]) * (1.0f / D_MODEL);
  float rs = rsqrtf(var + 1e-5f);
#pragma unroll
  for (int i = 0; i < 4; i++) {
    int d = t + i*256;
    float o = (v[i] - mu) * rs * g[d] + be[d];
    outf[(size_t)row * D_MODEL + d] = o;
    if (outb) outb[(size_t)row * D_MODEL + d] = f2b(o);
  }
}

// ---------------------------------------------------------------- GEMM (B^T form)
// C[m][n] = sum_k A[m][k]*Bt[n][k], A/Bt bf16 K-contiguous. m97 structure:
// 128x128 tile, BK=32, 4 waves in 2x2, 16x16x32 MFMA, global_load_lds w=16.
#define BM 128
#define BN 128
#define BKT 32

#define GM_QKV 0
#define GM_ADDRES 1
#define GM_RELU 2

template<int MODE>
__global__ __launch_bounds__(256)
void gemm_bt(const unsigned short* __restrict__ A,
             const unsigned short* __restrict__ Bt,
             const float* __restrict__ bias0, const float* __restrict__ bias1,
             const float* __restrict__ bias2, const float* __restrict__ resid,
             float* __restrict__ outf, unsigned short* __restrict__ outb,
             unsigned short* __restrict__ qo, unsigned short* __restrict__ ko,
             unsigned short* __restrict__ vo,
             int M, int N, int K)
{
  __shared__ __align__(16) unsigned short sA[BM * BKT];
  __shared__ __align__(16) unsigned short sB[BN * BKT];
  int tid = threadIdx.x;
  int w = tid >> 6, lane = tid & 63;
  int lm = lane & 15, lq = lane >> 4;
  int wm = w & 1, wn = w >> 1;
  int n0 = blockIdx.x * BN, m0 = blockIdx.y * BM;

  f32x4 acc[4][4];
#pragma unroll
  for (int i = 0; i < 4; i++)
#pragma unroll
    for (int j = 0; j < 4; j++) acc[i][j] = (f32x4){0.f, 0.f, 0.f, 0.f};

  int srow = lane >> 2;               // 0..15
  int scol = (lane & 3) * 8;          // element offset in K
  const unsigned short* ga0 = A  + (size_t)(m0 + w*32 + srow) * K + scol;
  const unsigned short* ga1 = ga0 + (size_t)16 * K;
  const unsigned short* gb0 = Bt + (size_t)(n0 + w*32 + srow) * K + scol;
  const unsigned short* gb1 = gb0 + (size_t)16 * K;
  unsigned short* la0 = &sA[(w*32 +  0) * BKT];
  unsigned short* la1 = &sA[(w*32 + 16) * BKT];
  unsigned short* lb0 = &sB[(w*32 +  0) * BKT];
  unsigned short* lb1 = &sB[(w*32 + 16) * BKT];

  for (int kt = 0; kt < K; kt += BKT) {
    gload_lds16(ga0 + kt, la0);
    gload_lds16(ga1 + kt, la1);
    gload_lds16(gb0 + kt, lb0);
    gload_lds16(gb1 + kt, lb1);
    __syncthreads();
    bf16x8 af[4], bfr[4];
#pragma unroll
    for (int i = 0; i < 4; i++)
      af[i] = ld8(&sA[(wm*64 + i*16 + lm) * BKT + lq*8]);
#pragma unroll
    for (int j = 0; j < 4; j++)
      bfr[j] = ld8(&sB[(wn*64 + j*16 + lm) * BKT + lq*8]);
#pragma unroll
    for (int i = 0; i < 4; i++)
#pragma unroll
      for (int j = 0; j < 4; j++)
        acc[i][j] = __builtin_amdgcn_mfma_f32_16x16x32_bf16(af[i], bfr[j], acc[i][j], 0, 0, 0);
    __syncthreads();
  }

  // epilogue: C row = (lane>>4)*4 + r, col = lane&15 (verified m89/m91)
#pragma unroll
  for (int i = 0; i < 4; i++) {
#pragma unroll
    for (int j = 0; j < 4; j++) {
      int n = n0 + wn*64 + j*16 + lm;
#pragma unroll
      for (int r = 0; r < 4; r++) {
        int m = m0 + wm*64 + i*16 + lq*4 + r;
        float val = acc[i][j][r];
        if constexpr (MODE == GM_QKV) {
          int which = n >> 10, nn = n & 1023;
          const float* bb = (which == 0) ? bias0 : (which == 1) ? bias1 : bias2;
          val += bb[nn];
          int hh = nn >> 6, dk = nn & 63;
          int b = m >> 11, s = m & 2047;
          size_t bh = (size_t)(b * NH + hh);
          if (which == 0)      qo[(bh * SEQ + s) * DKH + dk] = f2b(val);
          else if (which == 1) ko[(bh * SEQ + s) * DKH + dk] = f2b(val);
          else                 vo[(bh * DKH + dk) * SEQ + s] = f2b(val);   // V transposed
        } else if constexpr (MODE == GM_ADDRES) {
          val += bias0[n] + resid[(size_t)m * N + n];
          outf[(size_t)m * N + n] = val;
        } else {  // GM_RELU
          val += bias0[n];
          val = fmaxf(val, 0.f);
          outb[(size_t)m * N + n] = f2b(val);
        }
      }
    }
  }
}

// ---------------------------------------------------------------- flash attention
// grid = B*NH*(SEQ/64); 4 waves/block, each wave owns 16 q rows, streams 32 keys.
__global__ __launch_bounds__(256)
void attn_kernel(const unsigned short* __restrict__ qb,
                 const unsigned short* __restrict__ kb,
                 const unsigned short* __restrict__ vtb,
                 const int* __restrict__ mask,
                 unsigned short* __restrict__ ctx)
{
  int lane = threadIdx.x & 63, w = threadIdx.x >> 6;
  int lm = lane & 15, lq = lane >> 4;
  int nqb = SEQ / 64;
  int qbi = blockIdx.x % nqb;
  int bh  = blockIdx.x / nqb;
  int b = bh / NH, hh = bh % NH;
  int q0 = qbi * 64 + w * 16;
  const unsigned short* qp = qb  + (size_t)bh * SEQ * DKH;
  const unsigned short* kp = kb  + (size_t)bh * SEQ * DKH;
  const unsigned short* vp = vtb + (size_t)bh * DKH * SEQ;
  const int* mp = mask + (size_t)b * SEQ;

  bf16x8 aq0 = ld8(qp + (q0 + lm) * DKH + lq*8);
  bf16x8 aq1 = ld8(qp + (q0 + lm) * DKH + lq*8 + 32);

  f32x4 o[4];
  float mi[4], li[4];
#pragma unroll
  for (int j = 0; j < 4; j++) o[j] = (f32x4){0.f, 0.f, 0.f, 0.f};
#pragma unroll
  for (int r = 0; r < 4; r++) { mi[r] = -1e30f; li[r] = 0.f; }

  __shared__ __align__(16) unsigned short pS[4][16*32];
  unsigned short* pw = &pS[w][0];
  const float scale = 0.125f;   // 1/sqrt(64)

  for (int kt = 0; kt < SEQ; kt += 32) {
    bf16x8 bk00 = ld8(kp + (kt      + lm) * DKH + lq*8);
    bf16x8 bk01 = ld8(kp + (kt      + lm) * DKH + lq*8 + 32);
    bf16x8 bk10 = ld8(kp + (kt + 16 + lm) * DKH + lq*8);
    bf16x8 bk11 = ld8(kp + (kt + 16 + lm) * DKH + lq*8 + 32);
    f32x4 s0 = (f32x4){0.f,0.f,0.f,0.f}, s1 = (f32x4){0.f,0.f,0.f,0.f};
    s0 = __builtin_amdgcn_mfma_f32_16x16x32_bf16(aq0, bk00, s0, 0, 0, 0);
    s0 = __builtin_amdgcn_mfma_f32_16x16x32_bf16(aq1, bk01, s0, 0, 0, 0);
    s1 = __builtin_amdgcn_mfma_f32_16x16x32_bf16(aq0, bk10, s1, 0, 0, 0);
    s1 = __builtin_amdgcn_mfma_f32_16x16x32_bf16(aq1, bk11, s1, 0, 0, 0);
    int mk0 = mp[kt + lm], mk1 = mp[kt + 16 + lm];
    float sv0[4], sv1[4], mt[4];
#pragma unroll
    for (int r = 0; r < 4; r++) {
      sv0[r] = mk0 ? s0[r] * scale : -1e9f;
      sv1[r] = mk1 ? s1[r] * scale : -1e9f;
      mt[r] = fmaxf(sv0[r], sv1[r]);
    }
#pragma unroll
    for (int off = 1; off < 16; off <<= 1)
#pragma unroll
      for (int r = 0; r < 4; r++) mt[r] = fmaxf(mt[r], __shfl_xor(mt[r], off));
    float al[4], ls[4];
#pragma unroll
    for (int r = 0; r < 4; r++) {
      float mn = fmaxf(mi[r], mt[r]);
      al[r] = __expf(mi[r] - mn);
      mi[r] = mn;
    }
#pragma unroll
    for (int r = 0; r < 4; r++) {
      float p0 = __expf(sv0[r] - mi[r]);
      float p1 = __expf(sv1[r] - mi[r]);
      ls[r] = p0 + p1;
      pw[(lq*4 + r) * 32 + lm]      = f2b(p0);
      pw[(lq*4 + r) * 32 + 16 + lm] = f2b(p1);
    }
#pragma unroll
    for (int off = 1; off < 16; off <<= 1)
#pragma unroll
      for (int r = 0; r < 4; r++) ls[r] += __shfl_xor(ls[r], off);
#pragma unroll
    for (int r = 0; r < 4; r++) li[r] = li[r] * al[r] + ls[r];
    bf16x8 ap = ld8(pw + lm*32 + lq*8);   // P in A-layout (same-wave DS is ordered)
#pragma unroll
    for (int jt = 0; jt < 4; jt++) {
      bf16x8 bv = ld8(vp + (jt*16 + lm) * SEQ + kt + lq*8);
#pragma unroll
      for (int r = 0; r < 4; r++) o[jt][r] *= al[r];
      o[jt] = __builtin_amdgcn_mfma_f32_16x16x32_bf16(ap, bv, o[jt], 0, 0, 0);
    }
  }
#pragma unroll
  for (int jt = 0; jt < 4; jt++)
#pragma unroll
    for (int r = 0; r < 4; r++) {
      float val = o[jt][r] / li[r];
      int s = q0 + lq*4 + r;
      ctx[((size_t)(b * SEQ + s)) * D_MODEL + hh * DKH + jt*16 + lm] = f2b(val);
    }
}

// ---------------------------------------------------------------- launcher
extern "C" void kernel_launch(void* const* d_in, const int* in_sizes, int n_in,
                              void* d_out, int out_size, void* d_ws, size_t ws_size,
                              hipStream_t stream) {
  const int*   x    = (const int*)d_in[0];
  const int*   mask = (const int*)d_in[1];
  const float* emb  = (const float*)d_in[2];
  const float* wq   = (const float*)d_in[3];
  const float* bq   = (const float*)d_in[4];
  const float* wk   = (const float*)d_in[5];
  const float* bk   = (const float*)d_in[6];
  const float* wv   = (const float*)d_in[7];
  const float* bv   = (const float*)d_in[8];
  const float* wo   = (const float*)d_in[9];
  const float* bo   = (const float*)d_in[10];
  const float* w1   = (const float*)d_in[11];
  const float* b1   = (const float*)d_in[12];
  const float* w2   = (const float*)d_in[13];
  const float* b2   = (const float*)d_in[14];
  const float* g1   = (const float*)d_in[15];
  const float* be1  = (const float*)d_in[16];
  const float* g2   = (const float*)d_in[17];
  const float* be2  = (const float*)d_in[18];
  const float* gf   = (const float*)d_in[19];
  const float* bfin = (const float*)d_in[20];

  const size_t DD = (size_t)D_MODEL * D_MODEL;       // 1M
  const size_t DDF = (size_t)D_MODEL * DFF_N;        // 4M
  char* p = (char*)d_ws;
  auto alloc = [&](size_t bytes) { void* r = (void*)p; p += (bytes + 255) & ~(size_t)255; return r; };
  unsigned short* qkvT = (unsigned short*)alloc(LAYERS * 3 * DD * 2);
  unsigned short* woT  = (unsigned short*)alloc(LAYERS * DD * 2);
  unsigned short* w1T  = (unsigned short*)alloc(LAYERS * DDF * 2);
  unsigned short* w2T  = (unsigned short*)alloc(LAYERS * DDF * 2);
  float*          h    = (float*)alloc((size_t)MROWS * D_MODEL * 4);
  unsigned short* hb   = (unsigned short*)alloc((size_t)MROWS * D_MODEL * 2);
  float*          t0   = (float*)alloc((size_t)MROWS * D_MODEL * 4);
  unsigned short* qB   = (unsigned short*)alloc((size_t)MROWS * D_MODEL * 2);
  unsigned short* kB   = (unsigned short*)alloc((size_t)MROWS * D_MODEL * 2);
  unsigned short* vB   = (unsigned short*)alloc((size_t)MROWS * D_MODEL * 2);
  unsigned short* ctx  = (unsigned short*)alloc((size_t)MROWS * D_MODEL * 2);
  unsigned short* ffa  = qB;   // lifetime-disjoint: reuse q/k/v/ctx region (64MB)

  // ---- weight prep (every call: ws is re-poisoned) ----
  for (int l = 0; l < LAYERS; l++) {
    transpose_cvt<<<dim3(32, 32), 256, 0, stream>>>(wq + l*DD, qkvT + l*3*DD,          D_MODEL, D_MODEL);
    transpose_cvt<<<dim3(32, 32), 256, 0, stream>>>(wk + l*DD, qkvT + l*3*DD + DD,     D_MODEL, D_MODEL);
    transpose_cvt<<<dim3(32, 32), 256, 0, stream>>>(wv + l*DD, qkvT + l*3*DD + 2*DD,   D_MODEL, D_MODEL);
    transpose_cvt<<<dim3(32, 32), 256, 0, stream>>>(wo + l*DD, woT + l*DD,             D_MODEL, D_MODEL);
    transpose_cvt<<<dim3(DFF_N/32, D_MODEL/32), 256, 0, stream>>>(w1 + l*DDF, w1T + l*DDF, D_MODEL, DFF_N);
    transpose_cvt<<<dim3(D_MODEL/32, DFF_N/32), 256, 0, stream>>>(w2 + l*DDF, w2T + l*DDF, DFF_N, D_MODEL);
  }

  embed_kernel<<<MROWS * D_MODEL / 256, 256, 0, stream>>>(x, emb, h, hb);

  for (int l = 0; l < LAYERS; l++) {
    gemm_bt<GM_QKV><<<dim3(3072/BN, MROWS/BM), 256, 0, stream>>>(
        hb, qkvT + l*3*DD, bq + l*D_MODEL, bk + l*D_MODEL, bv + l*D_MODEL,
        nullptr, nullptr, nullptr, qB, kB, vB, MROWS, 3072, D_MODEL);
    attn_kernel<<<BATCH*NH*(SEQ/64), 256, 0, stream>>>(qB, kB, vB, mask, ctx);
    gemm_bt<GM_ADDRES><<<dim3(D_MODEL/BN, MROWS/BM), 256, 0, stream>>>(
        ctx, woT + l*DD, bo + l*D_MODEL, nullptr, nullptr, h,
        t0, nullptr, nullptr, nullptr, nullptr, MROWS, D_MODEL, D_MODEL);
    ln_kernel<<<MROWS, 256, 0, stream>>>(t0, g1 + l*D_MODEL, be1 + l*D_MODEL, h, hb);
    gemm_bt<GM_RELU><<<dim3(DFF_N/BN, MROWS/BM), 256, 0, stream>>>(
        hb, w1T + l*DDF, b1 + l*DFF_N, nullptr, nullptr, nullptr,
        nullptr, ffa, nullptr, nullptr, nullptr, MROWS, DFF_N, D_MODEL);
    gemm_bt<GM_ADDRES><<<dim3(D_MODEL/BN, MROWS/BM), 256, 0, stream>>>(
        ffa, w2T + l*DDF, b2 + l*D_MODEL, nullptr, nullptr, h,
        t0, nullptr, nullptr, nullptr, nullptr, MROWS, D_MODEL, DFF_N);
    ln_kernel<<<MROWS, 256, 0, stream>>>(t0, g2 + l*D_MODEL, be2 + l*D_MODEL, h, hb);
  }

  ln_kernel<<<MROWS, 256, 0, stream>>>(h, gf, bfin, (float*)d_out, nullptr);
}